// Round 8
// baseline (351.299 us; speedup 1.0000x reference)
//
#include <hip/hip_runtime.h>
#include <hip/hip_bf16.h>
#include <type_traits>

using bf16 = __hip_bfloat16;
typedef __attribute__((ext_vector_type(8))) short bf16x8;   // 8 bf16 (4 VGPRs) — MFMA A/B frag
typedef __attribute__((ext_vector_type(4))) float floatx4;  // MFMA C/D frag

static constexpr int Bb = 2, S = 4096, D = 768, H = 6, HK = 2, HD = 128, REP = 3;
static constexpr int M_ROWS = Bb * S;   // 8192
static constexpr int NQKV = 1280;       // fused projection width: 768 Q + 256 K + 256 V

__device__ __forceinline__ floatx4 mfma16(bf16x8 a, bf16x8 b, floatx4 c) {
  return __builtin_amdgcn_mfma_f32_16x16x32_bf16(a, b, c, 0, 0, 0);
}

// async global->LDS, 16B/lane; LDS dest = wave-uniform base + lane*16
__device__ __forceinline__ void gld_lds16(const bf16* g, bf16* l) {
  __builtin_amdgcn_global_load_lds(
      (const __attribute__((address_space(1))) unsigned int*)g,
      (__attribute__((address_space(3))) unsigned int*)l, 16, 0, 0);
}

#if defined(__has_builtin)
#if __has_builtin(__builtin_amdgcn_exp2f)
#define EXP2F(x) __builtin_amdgcn_exp2f(x)
#endif
#endif
#ifndef EXP2F
#define EXP2F(x) exp2f(x)
#endif

// pack two fp32 -> 2x bf16 (round-half-up): bias + one v_perm_b32
__device__ __forceinline__ unsigned pk2(float a, float b) {
  unsigned ua = __builtin_bit_cast(unsigned, a) + 0x8000u;
  unsigned ub = __builtin_bit_cast(unsigned, b) + 0x8000u;
#if defined(__has_builtin) && __has_builtin(__builtin_amdgcn_perm)
  return __builtin_amdgcn_perm(ub, ua, 0x07060302);  // {ub.hi16, ua.hi16}
#else
  return (ua >> 16) | (ub & 0xffff0000u);
#endif
}

// ---------------- fused fp32 -> bf16 convert for all 5 inputs ----------------
static constexpr size_t E_X  = (size_t)M_ROWS * D;                 // 6291456
static constexpr size_t E_WQ = E_X + (size_t)H * HD * D;           // +589824
static constexpr size_t E_WK = E_WQ + (size_t)HK * HD * D;         // +196608
static constexpr size_t E_WV = E_WK + (size_t)HK * HD * D;         // +196608
static constexpr size_t E_WO = E_WV + (size_t)D * H * HD;          // +589824 = 7864320

__global__ __launch_bounds__(256) void cvt_all(const float* __restrict__ x,
                                               const float* __restrict__ wq,
                                               const float* __restrict__ wk,
                                               const float* __restrict__ wv,
                                               const float* __restrict__ wo,
                                               bf16* __restrict__ xb,
                                               bf16* __restrict__ wqkvb,
                                               bf16* __restrict__ wob, float qscale) {
  size_t i = ((size_t)blockIdx.x * 256 + threadIdx.x) * 4;
  const float* src;
  bf16* dst;
  float s = 1.f;
  size_t off;
  if (i < E_X)        { src = x;  dst = xb;                 off = i; }
  else if (i < E_WQ)  { src = wq; dst = wqkvb;              off = i - E_X; s = qscale; }
  else if (i < E_WK)  { src = wk; dst = wqkvb + 589824;     off = i - E_WQ; }
  else if (i < E_WV)  { src = wv; dst = wqkvb + 786432;     off = i - E_WK; }
  else                { src = wo; dst = wob;                off = i - E_WV; }
  float4 v = *(const float4*)(src + off);
  uint2 st;
  st.x = pk2(v.x * s, v.y * s);
  st.y = pk2(v.z * s, v.w * s);
  *(uint2*)(dst + off) = st;
}

// ---------------- GEMM: C[M,N] = A[M,K] @ W[N,K]^T  (BK=64, m97-style staging) ----------------
template <typename OutT, bool VT_FUSE>
__global__ __launch_bounds__(256, 3) void gemm_bt(const bf16* __restrict__ A,
                                                  const bf16* __restrict__ W,
                                                  OutT* __restrict__ C,
                                                  bf16* __restrict__ Vt,
                                                  int M, int N, int K) {
  const int tid = threadIdx.x;
  const int wave = tid >> 6, lane = tid & 63;
  const int quad = lane >> 4, lq = lane & 15;
  const int m0 = blockIdx.x * 128, n0 = blockIdx.y * 128;
  const int wm = (wave & 1) * 64, wn = (wave >> 1) * 64;

  __shared__ __align__(16) bf16 As[128 * 64];  // 16 KB
  __shared__ __align__(16) bf16 Ws[128 * 64];  // 16 KB

  floatx4 acc[4][4] = {};

  const int srow = lane >> 3, sc = lane & 7;  // staging: 8 rows x 8 chunks per issue

  for (int k0 = 0; k0 < K; k0 += 64) {
#pragma unroll
    for (int i = 0; i < 4; ++i) {
      int ig = wave * 4 + i;               // 0..15
      int r = ig * 8 + srow;               // 0..127
      int c = sc ^ (r & 7);
      gld_lds16(&A[(size_t)(m0 + r) * K + k0 + c * 8], &As[ig * 512]);
      gld_lds16(&W[(size_t)(n0 + r) * K + k0 + c * 8], &Ws[ig * 512]);
    }
    __syncthreads();
#pragma unroll
    for (int kh = 0; kh < 2; ++kh) {
      bf16x8 af[4], wf[4];
#pragma unroll
      for (int i = 0; i < 4; ++i) {
        int ra = wm + i * 16 + lq, rw = wn + i * 16 + lq;
        af[i] = *(const bf16x8*)&As[ra * 64 + (((kh * 4 + quad) ^ (ra & 7)) * 8)];
        wf[i] = *(const bf16x8*)&Ws[rw * 64 + (((kh * 4 + quad) ^ (rw & 7)) * 8)];
      }
#pragma unroll
      for (int i = 0; i < 4; ++i)
#pragma unroll
        for (int j = 0; j < 4; ++j) acc[i][j] = mfma16(af[i], wf[j], acc[i][j]);
    }
    __syncthreads();
  }

  if (VT_FUSE && n0 >= 1024) {
    // V projection tile -> Vt[b][g][d][s] via col-XOR-swizzled per-wave LDS transpose.
    bf16* tb = (wave < 2 ? As : Ws) + (wave & 1) * 4096;
    char* tc = (char*)tb;
#pragma unroll
    for (int i = 0; i < 4; ++i)
#pragma unroll
      for (int j = 0; j < 4; ++j) {
        uint2 st;
        st.x = pk2(acc[i][j][0], acc[i][j][1]);
        st.y = pk2(acc[i][j][2], acc[i][j][3]);
        int col = j * 16 + lq;
        int cc = (i * 2 + (quad >> 1)) ^ (col & 7);
        *(uint2*)(tc + col * 128 + cc * 16 + (quad & 1) * 8) = st;
      }
    const int b = m0 >> 12;  // uniform per block (128-row tiles never cross S)
    const int dd_off = lane >> 3, schunk = lane & 7;
    const int sbase = (m0 & 4095) + wm + schunk * 8;
#pragma unroll
    for (int e = 0; e < 8; ++e) {
      int cl = e * 8 + dd_off;                      // local col 0..63
      int col = (n0 - 1024) + wn + cl;              // 0..255
      int gg = col >> 7, dd = col & 127;
      bf16x8 vv = *(const bf16x8*)(tc + cl * 128 + ((schunk ^ (cl & 7)) * 16));
      *(bf16x8*)&Vt[((size_t)(b * HK + gg) * HD + dd) * S + sbase] = vv;
    }
    return;
  }
#pragma unroll
  for (int i = 0; i < 4; ++i)
#pragma unroll
    for (int j = 0; j < 4; ++j)
#pragma unroll
      for (int r = 0; r < 4; ++r) {
        int row = m0 + wm + i * 16 + quad * 4 + r;
        int col = n0 + wn + j * 16 + lq;
        float v = acc[i][j][r];
        if constexpr (std::is_same_v<OutT, float>)
          C[(size_t)row * N + col] = v;
        else
          C[(size_t)row * N + col] = __float2bfloat16(v);
      }
}

// ---------------- Flash attention: barrier-free K-loop, K/V fragments in registers ----------------
// Block: 256 thr = 4 waves; wave pair (half) covers KV range [half*2048, +2048), KV tile 32.
// Each wave loads its own K/V MFMA fragments straight from global (L2-hot, 64B segments),
// prefetching the next tile into the just-freed registers mid-iteration. No __syncthreads
// in the K-loop -> waves slip freely (per-wave fine-grained vmcnt instead of barrier drain).
// LDS: per-wave Pt round-trip (same-wave, no barrier) + end-of-kernel half-combine only.
__global__ __launch_bounds__(256, 2) void flash_attn(const bf16* __restrict__ QKV,
                                                     const bf16* __restrict__ Vt,
                                                     bf16* __restrict__ O) {
  const int bid = blockIdx.x;
  const int bg = (bid & 7) >> 1;                 // 0..3 -> (b,g), XCD-clustered
  const int b = bg >> 1, g = bg & 1;
  const int qt = ((bid >> 3) << 1) | (bid & 1);  // 0..127
  const int q0 = qt * 32;

  const int tid = threadIdx.x;
  const int w = tid >> 6, lane = tid & 63;
  const int half = w >> 1, wp = w & 1;           // KV-half, index within pair
  const int quad = lane >> 4, lq = lane & 15;

  // LDS: Pt [wave][head][16*32] @0 (12 KB) | oscr 48 KB @12288 | lscr 1.5 KB @61440
  __shared__ __align__(16) char smem[62976];
  bf16* Pt = (bf16*)smem;

  const bf16* Kg = QKV + ((size_t)b * S + half * 2048) * NQKV + H * HD + g * HD;
  const bf16* Vg = Vt + (size_t)(b * HK + g) * HD * S + half * 2048;

  // Q fragments: B-operand layout (n=lane&15 -> q-row, k=quad*8+j -> d)
  const bf16* Qg = QKV + ((size_t)b * S + q0 + wp * 16 + lq) * NQKV + g * REP * HD;
  bf16x8 qf[3][4];
#pragma unroll
  for (int u = 0; u < 3; ++u)
#pragma unroll
    for (int kk = 0; kk < 4; ++kk)
      qf[u][kk] = *(const bf16x8*)(Qg + u * HD + kk * 32 + quad * 8);

  bf16x8 ones;
#pragma unroll
  for (int j = 0; j < 8; ++j) ones[j] = (short)0x3F80;  // bf16 1.0

  // K/V fragments in registers (32 VGPRs each)
  bf16x8 kf[2][4];  // [tt][kk]: A-frag row t=tt*16+lq, k-elems kk*32+quad*8..
  bf16x8 vf[8];     // [dd]:     B-frag row d=dd*16+lq, t-elems quad*8..

  auto loadK = [&](int t0) {
#pragma unroll
    for (int tt = 0; tt < 2; ++tt)
#pragma unroll
      for (int kk = 0; kk < 4; ++kk)
        kf[tt][kk] =
            *(const bf16x8*)(Kg + (size_t)(t0 + tt * 16 + lq) * NQKV + kk * 32 + quad * 8);
  };
  auto loadV = [&](int t0) {
#pragma unroll
    for (int dd = 0; dd < 8; ++dd)
      vf[dd] = *(const bf16x8*)(Vg + (size_t)(dd * 16 + lq) * S + t0 + quad * 8);
  };

  loadK(0);
  loadV(0);

  floatx4 o[3][8] = {};
  floatx4 lacc[3] = {};           // denominator via ones-MFMA (all regs = row-sum)
  const int sw = (lq >> 1) & 3;   // Pt swizzle key
  char* ptb0 = (char*)(Pt + (w * 3) * 512);

  for (int it = 0; it < 64; ++it) {
    const int tn = (it + 1 < 64 ? it + 1 : 63) * 32;  // clamped prefetch target

    // ---- S^T = K Q^T : kf reused by 3 heads ----
    floatx4 sf[3][2] = {};
#pragma unroll
    for (int tt = 0; tt < 2; ++tt)
#pragma unroll
      for (int kk = 0; kk < 4; ++kk)
#pragma unroll
        for (int u = 0; u < 3; ++u) sf[u][tt] = mfma16(kf[tt][kk], qf[u][kk], sf[u][tt]);

    // kf consumed -> prefetch next K tile (covered by softmax+PV span)
    loadK(tn);

    // ---- p = exp2(s); write P^T packed b64 (per-wave LDS, no barrier) ----
#pragma unroll
    for (int u = 0; u < 3; ++u) {
      char* ptb = ptb0 + u * 1024;
#pragma unroll
      for (int tt = 0; tt < 2; ++tt) {
        float p0 = EXP2F(sf[u][tt][0]), p1 = EXP2F(sf[u][tt][1]);
        float p2 = EXP2F(sf[u][tt][2]), p3 = EXP2F(sf[u][tt][3]);
        uint2 pkv;
        pkv.x = pk2(p0, p1);
        pkv.y = pk2(p2, p3);
        int cc = (tt * 2 + (quad >> 1)) ^ sw;
        *(uint2*)(ptb + lq * 64 + cc * 16 + (quad & 1) * 8) = pkv;
      }
    }

    // ---- read P^T B-frags (same-wave LDS, in-order) ----
    bf16x8 pf[3];
#pragma unroll
    for (int u = 0; u < 3; ++u)
      pf[u] = *(const bf16x8*)(ptb0 + u * 1024 + lq * 64 + ((quad ^ sw) * 16));

    // ---- denominators: l += 1^T P^T ----
#pragma unroll
    for (int u = 0; u < 3; ++u) lacc[u] = mfma16(ones, pf[u], lacc[u]);

    // ---- O^T += V^T P^T : vf reused by 3 heads ----
#pragma unroll
    for (int dd = 0; dd < 8; ++dd)
#pragma unroll
      for (int u = 0; u < 3; ++u) o[u][dd] = mfma16(vf[dd], pf[u], o[u][dd]);

    // vf consumed -> prefetch next V tile (covered by next iter's S^T+softmax)
    loadV(tn);
  }

  // ---- combine halves in LDS (dedicated region; Pt may still be live in lagging waves) ----
  floatx4* oscr = (floatx4*)(smem + 12288);  // [pair_slot(0..5)][dd][lane]
  float* lscr = (float*)(smem + 61440);      // [pair_slot][lane]
  if (half == 1) {
#pragma unroll
    for (int u = 0; u < 3; ++u) {
#pragma unroll
      for (int dd = 0; dd < 8; ++dd)
        oscr[((wp * 3 + u) * 8 + dd) * 64 + lane] = o[u][dd];
      lscr[(wp * 3 + u) * 64 + lane] = lacc[u][0];
    }
  }
  __syncthreads();
  if (half == 0) {
    const size_t row = (size_t)b * S + q0 + wp * 16 + lq;
#pragma unroll
    for (int u = 0; u < 3; ++u) {
      float l = lacc[u][0] + lscr[(wp * 3 + u) * 64 + lane];
      float rinv = 1.0f / l;
#pragma unroll
      for (int dd = 0; dd < 8; ++dd) {
        floatx4 oc = o[u][dd] + oscr[((wp * 3 + u) * 8 + dd) * 64 + lane];
        uint2 st;
        st.x = pk2(oc[0] * rinv, oc[1] * rinv);
        st.y = pk2(oc[2] * rinv, oc[3] * rinv);
        int col = (g * REP + u) * HD + dd * 16 + quad * 4;
        *(uint2*)&O[row * (H * HD) + col] = st;
      }
    }
  }
}

// ---------------- launch ----------------
static inline size_t al256(size_t x) { return (x + 255) & ~size_t(255); }

extern "C" void kernel_launch(void* const* d_in, const int* in_sizes, int n_in,
                              void* d_out, int out_size, void* d_ws, size_t ws_size,
                              hipStream_t stream) {
  const float* x  = (const float*)d_in[0];
  const float* wq = (const float*)d_in[1];
  const float* wk = (const float*)d_in[2];
  const float* wv = (const float*)d_in[3];
  const float* wo = (const float*)d_in[4];
  float* out = (float*)d_out;

  char* w = (char*)d_ws;
  size_t off = 0;
  auto carve = [&](size_t elems) {
    bf16* p = (bf16*)(w + off);
    off = al256(off + elems * sizeof(bf16));
    return p;
  };
  bf16* xb    = carve((size_t)M_ROWS * D);
  bf16* wqkvb = carve((size_t)NQKV * D);  // wq(768) | wk(256) | wv(256) rows
  bf16* wob   = carve((size_t)D * (H * HD));
  bf16* QKVb  = carve((size_t)M_ROWS * NQKV);
  bf16* Vtb   = carve((size_t)M_ROWS * (HK * HD));
  bf16* Ab    = carve((size_t)M_ROWS * (H * HD));

  // (1/sqrt(128)) * log2(e), folded into wq: scores come out in log2 domain
  const float qscale = 0.1275174465f;

  cvt_all<<<(int)(E_WO / 1024), 256, 0, stream>>>(x, wq, wk, wv, wo, xb, wqkvb, wob, qscale);

  // fused QKV projection: [8192,768] x [1280,768]^T -> [8192,1280]; V tiles -> Vt transposed
  gemm_bt<bf16, true><<<dim3(M_ROWS / 128, NQKV / 128), 256, 0, stream>>>(
      xb, wqkvb, QKVb, Vtb, M_ROWS, NQKV, D);

  flash_attn<<<512, 256, 0, stream>>>(QKVb, Vtb, Ab);

  gemm_bt<float, false><<<dim3(M_ROWS / 128, D / 128), 256, 0, stream>>>(
      Ab, wob, out, nullptr, M_ROWS, D, H * HD);
}

// Round 9
// 240.539 us; speedup vs baseline: 1.4605x; 1.4605x over previous
//
#include <hip/hip_runtime.h>
#include <hip/hip_bf16.h>
#include <type_traits>

using bf16 = __hip_bfloat16;
typedef __attribute__((ext_vector_type(8))) short bf16x8;   // 8 bf16 (4 VGPRs) — MFMA A/B frag
typedef __attribute__((ext_vector_type(4))) float floatx4;  // MFMA C/D frag

static constexpr int Bb = 2, S = 4096, D = 768, H = 6, HK = 2, HD = 128, REP = 3;
static constexpr int M_ROWS = Bb * S;   // 8192
static constexpr int NQKV = 1280;       // fused projection width: 768 Q + 256 K + 256 V

__device__ __forceinline__ floatx4 mfma16(bf16x8 a, bf16x8 b, floatx4 c) {
  return __builtin_amdgcn_mfma_f32_16x16x32_bf16(a, b, c, 0, 0, 0);
}

// async global->LDS, 16B/lane; LDS dest = wave-uniform base + lane*16
__device__ __forceinline__ void gld_lds16(const bf16* g, bf16* l) {
  __builtin_amdgcn_global_load_lds(
      (const __attribute__((address_space(1))) unsigned int*)g,
      (__attribute__((address_space(3))) unsigned int*)l, 16, 0, 0);
}

#if defined(__has_builtin)
#if __has_builtin(__builtin_amdgcn_exp2f)
#define EXP2F(x) __builtin_amdgcn_exp2f(x)
#endif
#endif
#ifndef EXP2F
#define EXP2F(x) exp2f(x)
#endif

// pack two fp32 -> 2x bf16 (round-half-up): bias + one v_perm_b32
__device__ __forceinline__ unsigned pk2(float a, float b) {
  unsigned ua = __builtin_bit_cast(unsigned, a) + 0x8000u;
  unsigned ub = __builtin_bit_cast(unsigned, b) + 0x8000u;
#if defined(__has_builtin) && __has_builtin(__builtin_amdgcn_perm)
  return __builtin_amdgcn_perm(ub, ua, 0x07060302);  // {ub.hi16, ua.hi16}
#else
  return (ua >> 16) | (ub & 0xffff0000u);
#endif
}

// ---------------- fused fp32 -> bf16 convert for all 5 inputs ----------------
static constexpr size_t E_X  = (size_t)M_ROWS * D;                 // 6291456
static constexpr size_t E_WQ = E_X + (size_t)H * HD * D;           // +589824
static constexpr size_t E_WK = E_WQ + (size_t)HK * HD * D;         // +196608
static constexpr size_t E_WV = E_WK + (size_t)HK * HD * D;         // +196608
static constexpr size_t E_WO = E_WV + (size_t)D * H * HD;          // +589824 = 7864320

__global__ __launch_bounds__(256) void cvt_all(const float* __restrict__ x,
                                               const float* __restrict__ wq,
                                               const float* __restrict__ wk,
                                               const float* __restrict__ wv,
                                               const float* __restrict__ wo,
                                               bf16* __restrict__ xb,
                                               bf16* __restrict__ wqkvb,
                                               bf16* __restrict__ wob, float qscale) {
  size_t i = ((size_t)blockIdx.x * 256 + threadIdx.x) * 4;
  const float* src;
  bf16* dst;
  float s = 1.f;
  size_t off;
  if (i < E_X)        { src = x;  dst = xb;                 off = i; }
  else if (i < E_WQ)  { src = wq; dst = wqkvb;              off = i - E_X; s = qscale; }
  else if (i < E_WK)  { src = wk; dst = wqkvb + 589824;     off = i - E_WQ; }
  else if (i < E_WV)  { src = wv; dst = wqkvb + 786432;     off = i - E_WK; }
  else                { src = wo; dst = wob;                off = i - E_WV; }
  float4 v = *(const float4*)(src + off);
  uint2 st;
  st.x = pk2(v.x * s, v.y * s);
  st.y = pk2(v.z * s, v.w * s);
  *(uint2*)(dst + off) = st;
}

// ---------------- GEMM: C[M,N] = A[M,K] @ W[N,K]^T  (BK=64, m97-style staging) ----------------
// 128x128 tile, global_load_lds width-16 into unpadded XOR-swizzled LDS.
// VT_FUSE: n-tiles with n0 >= 1024 are the V projection -> col-XOR-swizzled LDS transpose
// then coalesced b128 stores to Vt[b][g][d][t].
template <typename OutT, bool VT_FUSE>
__global__ __launch_bounds__(256, 3) void gemm_bt(const bf16* __restrict__ A,
                                                  const bf16* __restrict__ W,
                                                  OutT* __restrict__ C,
                                                  bf16* __restrict__ Vt,
                                                  int M, int N, int K) {
  const int tid = threadIdx.x;
  const int wave = tid >> 6, lane = tid & 63;
  const int quad = lane >> 4, lq = lane & 15;
  const int m0 = blockIdx.x * 128, n0 = blockIdx.y * 128;
  const int wm = (wave & 1) * 64, wn = (wave >> 1) * 64;

  __shared__ __align__(16) bf16 As[128 * 64];  // 16 KB
  __shared__ __align__(16) bf16 Ws[128 * 64];  // 16 KB

  floatx4 acc[4][4] = {};

  const int srow = lane >> 3, sc = lane & 7;  // staging: 8 rows x 8 chunks per issue

  for (int k0 = 0; k0 < K; k0 += 64) {
#pragma unroll
    for (int i = 0; i < 4; ++i) {
      int ig = wave * 4 + i;               // 0..15
      int r = ig * 8 + srow;               // 0..127
      int c = sc ^ (r & 7);
      gld_lds16(&A[(size_t)(m0 + r) * K + k0 + c * 8], &As[ig * 512]);
      gld_lds16(&W[(size_t)(n0 + r) * K + k0 + c * 8], &Ws[ig * 512]);
    }
    __syncthreads();
#pragma unroll
    for (int kh = 0; kh < 2; ++kh) {
      bf16x8 af[4], wf[4];
#pragma unroll
      for (int i = 0; i < 4; ++i) {
        int ra = wm + i * 16 + lq, rw = wn + i * 16 + lq;
        af[i] = *(const bf16x8*)&As[ra * 64 + (((kh * 4 + quad) ^ (ra & 7)) * 8)];
        wf[i] = *(const bf16x8*)&Ws[rw * 64 + (((kh * 4 + quad) ^ (rw & 7)) * 8)];
      }
#pragma unroll
      for (int i = 0; i < 4; ++i)
#pragma unroll
        for (int j = 0; j < 4; ++j) acc[i][j] = mfma16(af[i], wf[j], acc[i][j]);
    }
    __syncthreads();
  }

  if (VT_FUSE && n0 >= 1024) {
    bf16* tb = (wave < 2 ? As : Ws) + (wave & 1) * 4096;
    char* tc = (char*)tb;
#pragma unroll
    for (int i = 0; i < 4; ++i)
#pragma unroll
      for (int j = 0; j < 4; ++j) {
        uint2 st;
        st.x = pk2(acc[i][j][0], acc[i][j][1]);
        st.y = pk2(acc[i][j][2], acc[i][j][3]);
        int col = j * 16 + lq;
        int cc = (i * 2 + (quad >> 1)) ^ (col & 7);
        *(uint2*)(tc + col * 128 + cc * 16 + (quad & 1) * 8) = st;
      }
    const int b = m0 >> 12;  // uniform per block (128-row tiles never cross S)
    const int dd_off = lane >> 3, schunk = lane & 7;
    const int sbase = (m0 & 4095) + wm + schunk * 8;
#pragma unroll
    for (int e = 0; e < 8; ++e) {
      int cl = e * 8 + dd_off;                      // local col 0..63
      int col = (n0 - 1024) + wn + cl;              // 0..255
      int gg = col >> 7, dd = col & 127;
      bf16x8 vv = *(const bf16x8*)(tc + cl * 128 + ((schunk ^ (cl & 7)) * 16));
      *(bf16x8*)&Vt[((size_t)(b * HK + gg) * HD + dd) * S + sbase] = vv;
    }
    return;
  }
#pragma unroll
  for (int i = 0; i < 4; ++i)
#pragma unroll
    for (int j = 0; j < 4; ++j)
#pragma unroll
      for (int r = 0; r < 4; ++r) {
        int row = m0 + wm + i * 16 + quad * 4 + r;
        int col = n0 + wn + j * 16 + lq;
        float v = acc[i][j][r];
        if constexpr (std::is_same_v<OutT, float>)
          C[(size_t)row * N + col] = v;
        else
          C[(size_t)row * N + col] = __float2bfloat16(v);
      }
}

// ---------------- Flash attention: S-transposed, no-max softmax, intra-block split-K ----------------
// r7 structure (LDS DMA staging, dbuf, 1 barrier/iter, 2 blocks/CU) — register-resident K/V
// (r8) was 2x WORSE: per-wave global fragment loads can't be latency-hidden at 2 waves/SIMD.
// r9 delta: per-head fusion of exp -> Pt write -> pf read -> lacc -> PV, so PV(u) MFMAs
// overlap exp(u+1) VALU instead of the whole softmax being one serial bubble.
__global__ __launch_bounds__(256, 2) void flash_attn(const bf16* __restrict__ QKV,
                                                     const bf16* __restrict__ Vt,
                                                     bf16* __restrict__ O) {
  const int bid = blockIdx.x;
  const int bg = (bid & 7) >> 1;                 // 0..3 -> (b,g), XCD-clustered
  const int b = bg >> 1, g = bg & 1;
  const int qt = ((bid >> 3) << 1) | (bid & 1);  // 0..127
  const int q0 = qt * 32;

  const int tid = threadIdx.x;
  const int w = tid >> 6, lane = tid & 63;
  const int half = w >> 1, wp = w & 1;           // KV-half, index within pair
  const int quad = lane >> 4, lq = lane & 15;

  __shared__ __align__(16) char smem[77824];
  bf16* Ks = (bf16*)smem;            // [buf][half][32*128], chunk c at c^(trow&15)
  bf16* Vs = (bf16*)(smem + 32768);  // [buf][half][128*32], chunk c at c^((drow>>1)&3)
  bf16* Pt = (bf16*)(smem + 65536);  // [wave][head][16*32], chunk c at c^((m>>1)&3)

  const bf16* Kgh = QKV + (size_t)b * S * NQKV + H * HD + g * HD + (size_t)half * 2048 * NQKV;
  const bf16* Vgh = Vt + (size_t)(b * HK + g) * HD * S + half * 2048;

  auto stage = [&](int t0, int buf) {
    bf16* kd = Ks + (buf * 2 + half) * 4096;
    bf16* vd = Vs + (buf * 2 + half) * 4096;
#pragma unroll
    for (int i = 0; i < 4; ++i) {
      int ig = wp * 4 + i;                 // 0..7
      int tl = ig * 4 + (lane >> 4);       // 0..31
      int c = (lane & 15) ^ (tl & 15);
      gld_lds16(Kgh + (size_t)(t0 + tl) * NQKV + c * 8, kd + ig * 512);
    }
#pragma unroll
    for (int i = 0; i < 4; ++i) {
      int ig = wp * 4 + i;
      int dl = ig * 16 + (lane >> 2);      // 0..127
      int c = (lane & 3) ^ ((dl >> 1) & 3);
      gld_lds16(Vgh + (size_t)dl * S + t0 + c * 8, vd + ig * 512);
    }
  };

  stage(0, 0);  // prologue

  // Q fragments: B-operand layout (n=lane&15 -> q-row, k=quad*8+j -> d)
  const bf16* Qg = QKV + ((size_t)b * S + q0 + wp * 16 + lq) * NQKV + g * REP * HD;
  bf16x8 qf[3][4];
#pragma unroll
  for (int u = 0; u < 3; ++u)
#pragma unroll
    for (int kk = 0; kk < 4; ++kk)
      qf[u][kk] = *(const bf16x8*)(Qg + u * HD + kk * 32 + quad * 8);

  bf16x8 ones;
#pragma unroll
  for (int j = 0; j < 8; ++j) ones[j] = (short)0x3F80;  // bf16 1.0

  floatx4 o[3][8] = {};
  floatx4 lacc[3] = {};           // denominator via ones-MFMA (all regs = row-sum)
  const int sw = (lq >> 1) & 3;   // swizzle key

#pragma unroll 2
  for (int it = 0; it < 64; ++it) {
    const int cur = it & 1;
    __syncthreads();  // drains this wave's DMA (vmcnt) + all waves' prior-iter LDS use
    if (it + 1 < 64) stage((it + 1) * 32, cur ^ 1);

    const bf16* ks = Ks + (cur * 2 + half) * 4096;
    const bf16* vs = Vs + (cur * 2 + half) * 4096;

    // ---- S^T = K Q^T : 6 interleaved chains saturate the MFMA pipe ----
    floatx4 sf[3][2] = {};
#pragma unroll
    for (int tt = 0; tt < 2; ++tt)
#pragma unroll
      for (int kk = 0; kk < 4; ++kk) {
        int c = (kk * 4 + quad) ^ lq;  // t row = tt*16+lq -> key lq
        bf16x8 kf = *(const bf16x8*)&ks[(tt * 16 + lq) * 128 + c * 8];
#pragma unroll
        for (int u = 0; u < 3; ++u) sf[u][tt] = mfma16(kf, qf[u][kk], sf[u][tt]);
      }

    // ---- per-head: exp -> Pt write -> pf read -> lacc -> PV ----
    // PV(u) MFMAs become issueable while exp(u+1) runs on the VALU.
#pragma unroll
    for (int u = 0; u < 3; ++u) {
      char* ptb = (char*)(Pt + (w * 3 + u) * 512);
#pragma unroll
      for (int tt = 0; tt < 2; ++tt) {
        float p0 = EXP2F(sf[u][tt][0]), p1 = EXP2F(sf[u][tt][1]);
        float p2 = EXP2F(sf[u][tt][2]), p3 = EXP2F(sf[u][tt][3]);
        uint2 pkv;
        pkv.x = pk2(p0, p1);
        pkv.y = pk2(p2, p3);
        int cc = (tt * 2 + (quad >> 1)) ^ sw;
        *(uint2*)(ptb + lq * 64 + cc * 16 + (quad & 1) * 8) = pkv;
      }
      bf16x8 pf = *(const bf16x8*)(ptb + lq * 64 + ((quad ^ sw) * 16));
      lacc[u] = mfma16(ones, pf, lacc[u]);
#pragma unroll
      for (int dd = 0; dd < 8; ++dd) {
        bf16x8 vf = *(const bf16x8*)&vs[(dd * 16 + lq) * 32 + ((quad ^ sw) * 8)];
        o[u][dd] = mfma16(vf, pf, o[u][dd]);
      }
    }
  }

  // ---- combine halves in LDS (overlay on Ks/Vs region), then store ----
  __syncthreads();  // all waves done reading K/V/P
  floatx4* oscr = (floatx4*)smem;           // [pair_slot(0..5)][dd][lane]
  float* lscr = (float*)(smem + 49152);     // [pair_slot][lane]
  if (half == 1) {
#pragma unroll
    for (int u = 0; u < 3; ++u) {
#pragma unroll
      for (int dd = 0; dd < 8; ++dd)
        oscr[((wp * 3 + u) * 8 + dd) * 64 + lane] = o[u][dd];
      lscr[(wp * 3 + u) * 64 + lane] = lacc[u][0];
    }
  }
  __syncthreads();
  if (half == 0) {
    const size_t row = (size_t)b * S + q0 + wp * 16 + lq;
#pragma unroll
    for (int u = 0; u < 3; ++u) {
      float l = lacc[u][0] + lscr[(wp * 3 + u) * 64 + lane];
      float rinv = 1.0f / l;
#pragma unroll
      for (int dd = 0; dd < 8; ++dd) {
        floatx4 oc = o[u][dd] + oscr[((wp * 3 + u) * 8 + dd) * 64 + lane];
        uint2 st;
        st.x = pk2(oc[0] * rinv, oc[1] * rinv);
        st.y = pk2(oc[2] * rinv, oc[3] * rinv);
        int col = (g * REP + u) * HD + dd * 16 + quad * 4;
        *(uint2*)&O[row * (H * HD) + col] = st;
      }
    }
  }
}

// ---------------- launch ----------------
static inline size_t al256(size_t x) { return (x + 255) & ~size_t(255); }

extern "C" void kernel_launch(void* const* d_in, const int* in_sizes, int n_in,
                              void* d_out, int out_size, void* d_ws, size_t ws_size,
                              hipStream_t stream) {
  const float* x  = (const float*)d_in[0];
  const float* wq = (const float*)d_in[1];
  const float* wk = (const float*)d_in[2];
  const float* wv = (const float*)d_in[3];
  const float* wo = (const float*)d_in[4];
  float* out = (float*)d_out;

  char* w = (char*)d_ws;
  size_t off = 0;
  auto carve = [&](size_t elems) {
    bf16* p = (bf16*)(w + off);
    off = al256(off + elems * sizeof(bf16));
    return p;
  };
  bf16* xb    = carve((size_t)M_ROWS * D);
  bf16* wqkvb = carve((size_t)NQKV * D);  // wq(768) | wk(256) | wv(256) rows
  bf16* wob   = carve((size_t)D * (H * HD));
  bf16* QKVb  = carve((size_t)M_ROWS * NQKV);
  bf16* Vtb   = carve((size_t)M_ROWS * (HK * HD));
  bf16* Ab    = carve((size_t)M_ROWS * (H * HD));

  // (1/sqrt(128)) * log2(e), folded into wq: scores come out in log2 domain
  const float qscale = 0.1275174465f;

  cvt_all<<<(int)(E_WO / 1024), 256, 0, stream>>>(x, wq, wk, wv, wo, xb, wqkvb, wob, qscale);

  // fused QKV projection: [8192,768] x [1280,768]^T -> [8192,1280]; V tiles -> Vt transposed
  gemm_bt<bf16, true><<<dim3(M_ROWS / 128, NQKV / 128), 256, 0, stream>>>(
      xb, wqkvb, QKVb, Vtb, M_ROWS, NQKV, D);

  flash_attn<<<512, 256, 0, stream>>>(QKVb, Vtb, Ab);

  gemm_bt<float, false><<<dim3(M_ROWS / 128, D / 128), 256, 0, stream>>>(
      Ab, wob, out, nullptr, M_ROWS, D, H * HD);
}

// Round 11
// 226.928 us; speedup vs baseline: 1.5481x; 1.0600x over previous
//
#include <hip/hip_runtime.h>
#include <hip/hip_bf16.h>
#include <type_traits>

using bf16 = __hip_bfloat16;
typedef __attribute__((ext_vector_type(8))) short bf16x8;   // 8 bf16 (4 VGPRs) — MFMA A/B frag
typedef __attribute__((ext_vector_type(4))) float floatx4;  // MFMA C/D frag

static constexpr int Bb = 2, S = 4096, D = 768, H = 6, HK = 2, HD = 128, REP = 3;
static constexpr int M_ROWS = Bb * S;   // 8192
static constexpr int NQKV = 1280;       // fused projection width: 768 Q + 256 K + 256 V

__device__ __forceinline__ floatx4 mfma16(bf16x8 a, bf16x8 b, floatx4 c) {
  return __builtin_amdgcn_mfma_f32_16x16x32_bf16(a, b, c, 0, 0, 0);
}

// async global->LDS, 16B/lane; LDS dest = wave-uniform base + lane*16
__device__ __forceinline__ void gld_lds16(const bf16* g, bf16* l) {
  __builtin_amdgcn_global_load_lds(
      (const __attribute__((address_space(1))) unsigned int*)g,
      (__attribute__((address_space(3))) unsigned int*)l, 16, 0, 0);
}

#if defined(__has_builtin)
#if __has_builtin(__builtin_amdgcn_exp2f)
#define EXP2F(x) __builtin_amdgcn_exp2f(x)
#endif
#endif
#ifndef EXP2F
#define EXP2F(x) exp2f(x)
#endif

// pack two fp32 -> 2x bf16 (round-half-up): bias + one v_perm_b32
__device__ __forceinline__ unsigned pk2(float a, float b) {
  unsigned ua = __builtin_bit_cast(unsigned, a) + 0x8000u;
  unsigned ub = __builtin_bit_cast(unsigned, b) + 0x8000u;
#if defined(__has_builtin) && __has_builtin(__builtin_amdgcn_perm)
  return __builtin_amdgcn_perm(ub, ua, 0x07060302);  // {ub.hi16, ua.hi16}
#else
  return (ua >> 16) | (ub & 0xffff0000u);
#endif
}

// ---------------- fused fp32 -> bf16 convert for all 5 inputs ----------------
static constexpr size_t E_X  = (size_t)M_ROWS * D;                 // 6291456
static constexpr size_t E_WQ = E_X + (size_t)H * HD * D;           // +589824
static constexpr size_t E_WK = E_WQ + (size_t)HK * HD * D;         // +196608
static constexpr size_t E_WV = E_WK + (size_t)HK * HD * D;         // +196608
static constexpr size_t E_WO = E_WV + (size_t)D * H * HD;          // +589824 = 7864320

__global__ __launch_bounds__(256) void cvt_all(const float* __restrict__ x,
                                               const float* __restrict__ wq,
                                               const float* __restrict__ wk,
                                               const float* __restrict__ wv,
                                               const float* __restrict__ wo,
                                               bf16* __restrict__ xb,
                                               bf16* __restrict__ wqkvb,
                                               bf16* __restrict__ wob, float qscale) {
  size_t i = ((size_t)blockIdx.x * 256 + threadIdx.x) * 4;
  const float* src;
  bf16* dst;
  float s = 1.f;
  size_t off;
  if (i < E_X)        { src = x;  dst = xb;                 off = i; }
  else if (i < E_WQ)  { src = wq; dst = wqkvb;              off = i - E_X; s = qscale; }
  else if (i < E_WK)  { src = wk; dst = wqkvb + 589824;     off = i - E_WQ; }
  else if (i < E_WV)  { src = wv; dst = wqkvb + 786432;     off = i - E_WK; }
  else                { src = wo; dst = wob;                off = i - E_WV; }
  float4 v = *(const float4*)(src + off);
  uint2 st;
  st.x = pk2(v.x * s, v.y * s);
  st.y = pk2(v.z * s, v.w * s);
  *(uint2*)(dst + off) = st;
}

// ---------------- GEMM: C[M,N] = A[M,K] @ W[N,K]^T  (BK=64, m97-style staging) ----------------
// 128x128 tile, global_load_lds width-16 into unpadded XOR-swizzled LDS.
// VT_FUSE: n-tiles with n0 >= 1024 are the V projection -> col-XOR-swizzled LDS transpose
// then coalesced b128 stores to Vt[b][g][d][t].
template <typename OutT, bool VT_FUSE>
__global__ __launch_bounds__(256, 3) void gemm_bt(const bf16* __restrict__ A,
                                                  const bf16* __restrict__ W,
                                                  OutT* __restrict__ C,
                                                  bf16* __restrict__ Vt,
                                                  int M, int N, int K) {
  const int tid = threadIdx.x;
  const int wave = tid >> 6, lane = tid & 63;
  const int quad = lane >> 4, lq = lane & 15;
  const int m0 = blockIdx.x * 128, n0 = blockIdx.y * 128;
  const int wm = (wave & 1) * 64, wn = (wave >> 1) * 64;

  __shared__ __align__(16) bf16 As[128 * 64];  // 16 KB
  __shared__ __align__(16) bf16 Ws[128 * 64];  // 16 KB

  floatx4 acc[4][4] = {};

  const int srow = lane >> 3, sc = lane & 7;  // staging: 8 rows x 8 chunks per issue

  for (int k0 = 0; k0 < K; k0 += 64) {
#pragma unroll
    for (int i = 0; i < 4; ++i) {
      int ig = wave * 4 + i;               // 0..15
      int r = ig * 8 + srow;               // 0..127
      int c = sc ^ (r & 7);
      gld_lds16(&A[(size_t)(m0 + r) * K + k0 + c * 8], &As[ig * 512]);
      gld_lds16(&W[(size_t)(n0 + r) * K + k0 + c * 8], &Ws[ig * 512]);
    }
    __syncthreads();
#pragma unroll
    for (int kh = 0; kh < 2; ++kh) {
      bf16x8 af[4], wf[4];
#pragma unroll
      for (int i = 0; i < 4; ++i) {
        int ra = wm + i * 16 + lq, rw = wn + i * 16 + lq;
        af[i] = *(const bf16x8*)&As[ra * 64 + (((kh * 4 + quad) ^ (ra & 7)) * 8)];
        wf[i] = *(const bf16x8*)&Ws[rw * 64 + (((kh * 4 + quad) ^ (rw & 7)) * 8)];
      }
#pragma unroll
      for (int i = 0; i < 4; ++i)
#pragma unroll
        for (int j = 0; j < 4; ++j) acc[i][j] = mfma16(af[i], wf[j], acc[i][j]);
    }
    __syncthreads();
  }

  if (VT_FUSE && n0 >= 1024) {
    bf16* tb = (wave < 2 ? As : Ws) + (wave & 1) * 4096;
    char* tc = (char*)tb;
#pragma unroll
    for (int i = 0; i < 4; ++i)
#pragma unroll
      for (int j = 0; j < 4; ++j) {
        uint2 st;
        st.x = pk2(acc[i][j][0], acc[i][j][1]);
        st.y = pk2(acc[i][j][2], acc[i][j][3]);
        int col = j * 16 + lq;
        int cc = (i * 2 + (quad >> 1)) ^ (col & 7);
        *(uint2*)(tc + col * 128 + cc * 16 + (quad & 1) * 8) = st;
      }
    const int b = m0 >> 12;  // uniform per block (128-row tiles never cross S)
    const int dd_off = lane >> 3, schunk = lane & 7;
    const int sbase = (m0 & 4095) + wm + schunk * 8;
#pragma unroll
    for (int e = 0; e < 8; ++e) {
      int cl = e * 8 + dd_off;                      // local col 0..63
      int col = (n0 - 1024) + wn + cl;              // 0..255
      int gg = col >> 7, dd = col & 127;
      bf16x8 vv = *(const bf16x8*)(tc + cl * 128 + ((schunk ^ (cl & 7)) * 16));
      *(bf16x8*)&Vt[((size_t)(b * HK + gg) * HD + dd) * S + sbase] = vv;
    }
    return;
  }
#pragma unroll
  for (int i = 0; i < 4; ++i)
#pragma unroll
    for (int j = 0; j < 4; ++j)
#pragma unroll
      for (int r = 0; r < 4; ++r) {
        int row = m0 + wm + i * 16 + quad * 4 + r;
        int col = n0 + wn + j * 16 + lq;
        float v = acc[i][j][r];
        if constexpr (std::is_same_v<OutT, float>)
          C[(size_t)row * N + col] = v;
        else
          C[(size_t)row * N + col] = __float2bfloat16(v);
      }
}

// ---------------- Flash attention: S-transposed, no-max softmax, intra-block split-K ----------------
// BEST-KNOWN-GOOD (r7): LDS DMA staging, DOUBLE-buffered K/V, 1 barrier/iter, 2 blocks/CU.
// The dbuf is load-bearing for CORRECTNESS, not just speed: single-buffer (r10) raced
// (staging writes vs other waves' reads around the barrier) and failed absmax.
// Register-resident K/V (r8): 2x slower (per-wave vmcnt stalls at 2 waves/SIMD).
// Per-head softmax fusion (r9): 12% slower (serialized Pt write->read lgkmcnt waits).
// Plateau: 893 TF effective = 43% of 2075 TF ubench MFMA ceiling, MfmaUtil 38.5%.
__global__ __launch_bounds__(256, 2) void flash_attn(const bf16* __restrict__ QKV,
                                                     const bf16* __restrict__ Vt,
                                                     bf16* __restrict__ O) {
  const int bid = blockIdx.x;
  const int bg = (bid & 7) >> 1;                 // 0..3 -> (b,g), XCD-clustered
  const int b = bg >> 1, g = bg & 1;
  const int qt = ((bid >> 3) << 1) | (bid & 1);  // 0..127
  const int q0 = qt * 32;

  const int tid = threadIdx.x;
  const int w = tid >> 6, lane = tid & 63;
  const int half = w >> 1, wp = w & 1;           // KV-half, index within pair
  const int quad = lane >> 4, lq = lane & 15;

  __shared__ __align__(16) char smem[77824];
  bf16* Ks = (bf16*)smem;            // [buf][half][32*128], chunk c at c^(trow&15)
  bf16* Vs = (bf16*)(smem + 32768);  // [buf][half][128*32], chunk c at c^((drow>>1)&3)
  bf16* Pt = (bf16*)(smem + 65536);  // [wave][head][16*32], chunk c at c^((m>>1)&3)

  const bf16* Kgh = QKV + (size_t)b * S * NQKV + H * HD + g * HD + (size_t)half * 2048 * NQKV;
  const bf16* Vgh = Vt + (size_t)(b * HK + g) * HD * S + half * 2048;

  auto stage = [&](int t0, int buf) {
    bf16* kd = Ks + (buf * 2 + half) * 4096;
    bf16* vd = Vs + (buf * 2 + half) * 4096;
#pragma unroll
    for (int i = 0; i < 4; ++i) {
      int ig = wp * 4 + i;                 // 0..7
      int tl = ig * 4 + (lane >> 4);       // 0..31
      int c = (lane & 15) ^ (tl & 15);
      gld_lds16(Kgh + (size_t)(t0 + tl) * NQKV + c * 8, kd + ig * 512);
    }
#pragma unroll
    for (int i = 0; i < 4; ++i) {
      int ig = wp * 4 + i;
      int dl = ig * 16 + (lane >> 2);      // 0..127
      int c = (lane & 3) ^ ((dl >> 1) & 3);
      gld_lds16(Vgh + (size_t)dl * S + t0 + c * 8, vd + ig * 512);
    }
  };

  stage(0, 0);  // prologue

  // Q fragments: B-operand layout (n=lane&15 -> q-row, k=quad*8+j -> d)
  const bf16* Qg = QKV + ((size_t)b * S + q0 + wp * 16 + lq) * NQKV + g * REP * HD;
  bf16x8 qf[3][4];
#pragma unroll
  for (int u = 0; u < 3; ++u)
#pragma unroll
    for (int kk = 0; kk < 4; ++kk)
      qf[u][kk] = *(const bf16x8*)(Qg + u * HD + kk * 32 + quad * 8);

  bf16x8 ones;
#pragma unroll
  for (int j = 0; j < 8; ++j) ones[j] = (short)0x3F80;  // bf16 1.0

  floatx4 o[3][8] = {};
  floatx4 lacc[3] = {};           // denominator via ones-MFMA (all regs = row-sum)
  const int sw = (lq >> 1) & 3;   // swizzle key

#pragma unroll 2
  for (int it = 0; it < 64; ++it) {
    const int cur = it & 1;
    __syncthreads();  // drains this wave's DMA (vmcnt) + all waves' prior-iter LDS use
    if (it + 1 < 64) stage((it + 1) * 32, cur ^ 1);

    const bf16* ks = Ks + (cur * 2 + half) * 4096;
    const bf16* vs = Vs + (cur * 2 + half) * 4096;

    // ---- S^T = K Q^T : kf read once, reused by 3 heads ----
    floatx4 sf[3][2] = {};
#pragma unroll
    for (int tt = 0; tt < 2; ++tt)
#pragma unroll
      for (int kk = 0; kk < 4; ++kk) {
        int c = (kk * 4 + quad) ^ lq;  // t row = tt*16+lq -> key lq
        bf16x8 kf = *(const bf16x8*)&ks[(tt * 16 + lq) * 128 + c * 8];
#pragma unroll
        for (int u = 0; u < 3; ++u) sf[u][tt] = mfma16(kf, qf[u][kk], sf[u][tt]);
      }

    // ---- p = exp2(s); write P^T packed b64 (batch form: one write->read wait, all heads) ----
#pragma unroll
    for (int u = 0; u < 3; ++u) {
      char* ptb = (char*)(Pt + (w * 3 + u) * 512);
#pragma unroll
      for (int tt = 0; tt < 2; ++tt) {
        float p0 = EXP2F(sf[u][tt][0]), p1 = EXP2F(sf[u][tt][1]);
        float p2 = EXP2F(sf[u][tt][2]), p3 = EXP2F(sf[u][tt][3]);
        uint2 pkv;
        pkv.x = pk2(p0, p1);
        pkv.y = pk2(p2, p3);
        int cc = (tt * 2 + (quad >> 1)) ^ sw;
        *(uint2*)(ptb + lq * 64 + cc * 16 + (quad & 1) * 8) = pkv;
      }
    }

    // ---- read P^T B-frags (same-wave LDS, in-order) ----
    bf16x8 pf[3];
#pragma unroll
    for (int u = 0; u < 3; ++u) {
      const char* ptb = (const char*)(Pt + (w * 3 + u) * 512);
      pf[u] = *(const bf16x8*)(ptb + lq * 64 + ((quad ^ sw) * 16));
    }

    // ---- denominators: l += 1^T P^T ----
#pragma unroll
    for (int u = 0; u < 3; ++u) lacc[u] = mfma16(ones, pf[u], lacc[u]);

    // ---- O^T += V^T P^T : vf read once, reused by 3 heads ----
#pragma unroll
    for (int dd = 0; dd < 8; ++dd) {
      bf16x8 vf = *(const bf16x8*)&vs[(dd * 16 + lq) * 32 + ((quad ^ sw) * 8)];
#pragma unroll
      for (int u = 0; u < 3; ++u) o[u][dd] = mfma16(vf, pf[u], o[u][dd]);
    }
  }

  // ---- combine halves in LDS (overlay on Ks/Vs region), then store ----
  __syncthreads();  // all waves done reading K/V/P
  floatx4* oscr = (floatx4*)smem;           // [pair_slot(0..5)][dd][lane]
  float* lscr = (float*)(smem + 49152);     // [pair_slot][lane]
  if (half == 1) {
#pragma unroll
    for (int u = 0; u < 3; ++u) {
#pragma unroll
      for (int dd = 0; dd < 8; ++dd)
        oscr[((wp * 3 + u) * 8 + dd) * 64 + lane] = o[u][dd];
      lscr[(wp * 3 + u) * 64 + lane] = lacc[u][0];
    }
  }
  __syncthreads();
  if (half == 0) {
    const size_t row = (size_t)b * S + q0 + wp * 16 + lq;
#pragma unroll
    for (int u = 0; u < 3; ++u) {
      float l = lacc[u][0] + lscr[(wp * 3 + u) * 64 + lane];
      float rinv = 1.0f / l;
#pragma unroll
      for (int dd = 0; dd < 8; ++dd) {
        floatx4 oc = o[u][dd] + oscr[((wp * 3 + u) * 8 + dd) * 64 + lane];
        uint2 st;
        st.x = pk2(oc[0] * rinv, oc[1] * rinv);
        st.y = pk2(oc[2] * rinv, oc[3] * rinv);
        int col = (g * REP + u) * HD + dd * 16 + quad * 4;
        *(uint2*)&O[row * (H * HD) + col] = st;
      }
    }
  }
}

// ---------------- launch ----------------
static inline size_t al256(size_t x) { return (x + 255) & ~size_t(255); }

extern "C" void kernel_launch(void* const* d_in, const int* in_sizes, int n_in,
                              void* d_out, int out_size, void* d_ws, size_t ws_size,
                              hipStream_t stream) {
  const float* x  = (const float*)d_in[0];
  const float* wq = (const float*)d_in[1];
  const float* wk = (const float*)d_in[2];
  const float* wv = (const float*)d_in[3];
  const float* wo = (const float*)d_in[4];
  float* out = (float*)d_out;

  char* w = (char*)d_ws;
  size_t off = 0;
  auto carve = [&](size_t elems) {
    bf16* p = (bf16*)(w + off);
    off = al256(off + elems * sizeof(bf16));
    return p;
  };
  bf16* xb    = carve((size_t)M_ROWS * D);
  bf16* wqkvb = carve((size_t)NQKV * D);  // wq(768) | wk(256) | wv(256) rows
  bf16* wob   = carve((size_t)D * (H * HD));
  bf16* QKVb  = carve((size_t)M_ROWS * NQKV);
  bf16* Vtb   = carve((size_t)M_ROWS * (HK * HD));
  bf16* Ab    = carve((size_t)M_ROWS * (H * HD));

  // (1/sqrt(128)) * log2(e), folded into wq: scores come out in log2 domain
  const float qscale = 0.1275174465f;

  cvt_all<<<(int)(E_WO / 1024), 256, 0, stream>>>(x, wq, wk, wv, wo, xb, wqkvb, wob, qscale);

  // fused QKV projection: [8192,768] x [1280,768]^T -> [8192,1280]; V tiles -> Vt transposed
  gemm_bt<bf16, true><<<dim3(M_ROWS / 128, NQKV / 128), 256, 0, stream>>>(
      xb, wqkvb, QKVb, Vtb, M_ROWS, NQKV, D);

  flash_attn<<<512, 256, 0, stream>>>(QKVb, Vtb, Ab);

  gemm_bt<float, false><<<dim3(M_ROWS / 128, D / 128), 256, 0, stream>>>(
      Ab, wob, out, nullptr, M_ROWS, D, H * HD);
}

// Round 12
// 225.412 us; speedup vs baseline: 1.5585x; 1.0067x over previous
//
#include <hip/hip_runtime.h>
#include <hip/hip_bf16.h>
#include <type_traits>

using bf16 = __hip_bfloat16;
typedef __attribute__((ext_vector_type(8))) short bf16x8;   // 8 bf16 (4 VGPRs) — MFMA A/B frag
typedef __attribute__((ext_vector_type(4))) float floatx4;  // MFMA C/D frag

static constexpr int Bb = 2, S = 4096, D = 768, H = 6, HK = 2, HD = 128, REP = 3;
static constexpr int M_ROWS = Bb * S;   // 8192
static constexpr int NQKV = 1280;       // fused projection width: 768 Q + 256 K + 256 V

__device__ __forceinline__ floatx4 mfma16(bf16x8 a, bf16x8 b, floatx4 c) {
  return __builtin_amdgcn_mfma_f32_16x16x32_bf16(a, b, c, 0, 0, 0);
}

// async global->LDS, 16B/lane; LDS dest = wave-uniform base + lane*16
__device__ __forceinline__ void gld_lds16(const bf16* g, bf16* l) {
  __builtin_amdgcn_global_load_lds(
      (const __attribute__((address_space(1))) unsigned int*)g,
      (__attribute__((address_space(3))) unsigned int*)l, 16, 0, 0);
}

#if defined(__has_builtin)
#if __has_builtin(__builtin_amdgcn_exp2f)
#define EXP2F(x) __builtin_amdgcn_exp2f(x)
#endif
#endif
#ifndef EXP2F
#define EXP2F(x) exp2f(x)
#endif

// pack two fp32 -> 2x bf16 (round-half-up): bias + one v_perm_b32
__device__ __forceinline__ unsigned pk2(float a, float b) {
  unsigned ua = __builtin_bit_cast(unsigned, a) + 0x8000u;
  unsigned ub = __builtin_bit_cast(unsigned, b) + 0x8000u;
#if defined(__has_builtin) && __has_builtin(__builtin_amdgcn_perm)
  return __builtin_amdgcn_perm(ub, ua, 0x07060302);  // {ub.hi16, ua.hi16}
#else
  return (ua >> 16) | (ub & 0xffff0000u);
#endif
}

// ---------------- fused fp32 -> bf16 convert for all 5 inputs ----------------
static constexpr size_t E_X  = (size_t)M_ROWS * D;                 // 6291456
static constexpr size_t E_WQ = E_X + (size_t)H * HD * D;           // +589824
static constexpr size_t E_WK = E_WQ + (size_t)HK * HD * D;         // +196608
static constexpr size_t E_WV = E_WK + (size_t)HK * HD * D;         // +196608
static constexpr size_t E_WO = E_WV + (size_t)D * H * HD;          // +589824 = 7864320

__global__ __launch_bounds__(256) void cvt_all(const float* __restrict__ x,
                                               const float* __restrict__ wq,
                                               const float* __restrict__ wk,
                                               const float* __restrict__ wv,
                                               const float* __restrict__ wo,
                                               bf16* __restrict__ xb,
                                               bf16* __restrict__ wqkvb,
                                               bf16* __restrict__ wob, float qscale) {
  size_t i = ((size_t)blockIdx.x * 256 + threadIdx.x) * 4;
  const float* src;
  bf16* dst;
  float s = 1.f;
  size_t off;
  if (i < E_X)        { src = x;  dst = xb;                 off = i; }
  else if (i < E_WQ)  { src = wq; dst = wqkvb;              off = i - E_X; s = qscale; }
  else if (i < E_WK)  { src = wk; dst = wqkvb + 589824;     off = i - E_WQ; }
  else if (i < E_WV)  { src = wv; dst = wqkvb + 786432;     off = i - E_WK; }
  else                { src = wo; dst = wob;                off = i - E_WV; }
  float4 v = *(const float4*)(src + off);
  uint2 st;
  st.x = pk2(v.x * s, v.y * s);
  st.y = pk2(v.z * s, v.w * s);
  *(uint2*)(dst + off) = st;
}

// ---------------- GEMM: C[M,N] = A[M,K] @ W[N,K]^T  (BK=64, m97-style staging) ----------------
// 128x128 tile, global_load_lds width-16 into unpadded XOR-swizzled LDS.
// VT_FUSE: n-tiles with n0 >= 1024 are the V projection -> col-XOR-swizzled LDS transpose
// then coalesced b128 stores to Vt[b][g][d][t].
template <typename OutT, bool VT_FUSE>
__global__ __launch_bounds__(256, 3) void gemm_bt(const bf16* __restrict__ A,
                                                  const bf16* __restrict__ W,
                                                  OutT* __restrict__ C,
                                                  bf16* __restrict__ Vt,
                                                  int M, int N, int K) {
  const int tid = threadIdx.x;
  const int wave = tid >> 6, lane = tid & 63;
  const int quad = lane >> 4, lq = lane & 15;
  const int m0 = blockIdx.x * 128, n0 = blockIdx.y * 128;
  const int wm = (wave & 1) * 64, wn = (wave >> 1) * 64;

  __shared__ __align__(16) bf16 As[128 * 64];  // 16 KB
  __shared__ __align__(16) bf16 Ws[128 * 64];  // 16 KB

  floatx4 acc[4][4] = {};

  const int srow = lane >> 3, sc = lane & 7;  // staging: 8 rows x 8 chunks per issue

  for (int k0 = 0; k0 < K; k0 += 64) {
#pragma unroll
    for (int i = 0; i < 4; ++i) {
      int ig = wave * 4 + i;               // 0..15
      int r = ig * 8 + srow;               // 0..127
      int c = sc ^ (r & 7);
      gld_lds16(&A[(size_t)(m0 + r) * K + k0 + c * 8], &As[ig * 512]);
      gld_lds16(&W[(size_t)(n0 + r) * K + k0 + c * 8], &Ws[ig * 512]);
    }
    __syncthreads();
#pragma unroll
    for (int kh = 0; kh < 2; ++kh) {
      bf16x8 af[4], wf[4];
#pragma unroll
      for (int i = 0; i < 4; ++i) {
        int ra = wm + i * 16 + lq, rw = wn + i * 16 + lq;
        af[i] = *(const bf16x8*)&As[ra * 64 + (((kh * 4 + quad) ^ (ra & 7)) * 8)];
        wf[i] = *(const bf16x8*)&Ws[rw * 64 + (((kh * 4 + quad) ^ (rw & 7)) * 8)];
      }
#pragma unroll
      for (int i = 0; i < 4; ++i)
#pragma unroll
        for (int j = 0; j < 4; ++j) acc[i][j] = mfma16(af[i], wf[j], acc[i][j]);
    }
    __syncthreads();
  }

  if (VT_FUSE && n0 >= 1024) {
    bf16* tb = (wave < 2 ? As : Ws) + (wave & 1) * 4096;
    char* tc = (char*)tb;
#pragma unroll
    for (int i = 0; i < 4; ++i)
#pragma unroll
      for (int j = 0; j < 4; ++j) {
        uint2 st;
        st.x = pk2(acc[i][j][0], acc[i][j][1]);
        st.y = pk2(acc[i][j][2], acc[i][j][3]);
        int col = j * 16 + lq;
        int cc = (i * 2 + (quad >> 1)) ^ (col & 7);
        *(uint2*)(tc + col * 128 + cc * 16 + (quad & 1) * 8) = st;
      }
    const int b = m0 >> 12;  // uniform per block (128-row tiles never cross S)
    const int dd_off = lane >> 3, schunk = lane & 7;
    const int sbase = (m0 & 4095) + wm + schunk * 8;
#pragma unroll
    for (int e = 0; e < 8; ++e) {
      int cl = e * 8 + dd_off;                      // local col 0..63
      int col = (n0 - 1024) + wn + cl;              // 0..255
      int gg = col >> 7, dd = col & 127;
      bf16x8 vv = *(const bf16x8*)(tc + cl * 128 + ((schunk ^ (cl & 7)) * 16));
      *(bf16x8*)&Vt[((size_t)(b * HK + gg) * HD + dd) * S + sbase] = vv;
    }
    return;
  }
#pragma unroll
  for (int i = 0; i < 4; ++i)
#pragma unroll
    for (int j = 0; j < 4; ++j)
#pragma unroll
      for (int r = 0; r < 4; ++r) {
        int row = m0 + wm + i * 16 + quad * 4 + r;
        int col = n0 + wn + j * 16 + lq;
        float v = acc[i][j][r];
        if constexpr (std::is_same_v<OutT, float>)
          C[(size_t)row * N + col] = v;
        else
          C[(size_t)row * N + col] = __float2bfloat16(v);
      }
}

// ---------------- out-projection GEMM: 128x64 tile ----------------
// N=768 at 128x128 tiles gave only 384 blocks = 1.5 blocks/CU = 6 waves/CU — half the
// latency hiding of the QKV GEMM. 128x64 tiles -> 64x12 = 768 blocks = exactly 3/CU x 256,
// 12 waves/CU, single full round. Same k-accumulation order per element (bit-identical C).
__global__ __launch_bounds__(256, 3) void gemm_out(const bf16* __restrict__ A,
                                                   const bf16* __restrict__ W,
                                                   float* __restrict__ C,
                                                   int M, int N, int K) {
  const int tid = threadIdx.x;
  const int wave = tid >> 6, lane = tid & 63;
  const int quad = lane >> 4, lq = lane & 15;
  const int m0 = blockIdx.x * 128, n0 = blockIdx.y * 64;
  const int wm = (wave & 1) * 64, wn = (wave >> 1) * 32;

  __shared__ __align__(16) bf16 As[128 * 64];  // 16 KB
  __shared__ __align__(16) bf16 Ws[64 * 64];   // 8 KB

  floatx4 acc[4][2] = {};

  const int srow = lane >> 3, sc = lane & 7;  // staging: 8 rows x 8 chunks per issue

  for (int k0 = 0; k0 < K; k0 += 64) {
#pragma unroll
    for (int i = 0; i < 4; ++i) {
      int ig = wave * 4 + i;               // 0..15
      int r = ig * 8 + srow;               // 0..127
      int c = sc ^ (r & 7);
      gld_lds16(&A[(size_t)(m0 + r) * K + k0 + c * 8], &As[ig * 512]);
    }
#pragma unroll
    for (int i = 0; i < 2; ++i) {
      int ig = wave * 2 + i;               // 0..7
      int r = ig * 8 + srow;               // 0..63
      int c = sc ^ (r & 7);
      gld_lds16(&W[(size_t)(n0 + r) * K + k0 + c * 8], &Ws[ig * 512]);
    }
    __syncthreads();
#pragma unroll
    for (int kh = 0; kh < 2; ++kh) {
      bf16x8 af[4], wf[2];
#pragma unroll
      for (int i = 0; i < 4; ++i) {
        int ra = wm + i * 16 + lq;
        af[i] = *(const bf16x8*)&As[ra * 64 + (((kh * 4 + quad) ^ (ra & 7)) * 8)];
      }
#pragma unroll
      for (int j = 0; j < 2; ++j) {
        int rw = wn + j * 16 + lq;
        wf[j] = *(const bf16x8*)&Ws[rw * 64 + (((kh * 4 + quad) ^ (rw & 7)) * 8)];
      }
#pragma unroll
      for (int i = 0; i < 4; ++i)
#pragma unroll
        for (int j = 0; j < 2; ++j) acc[i][j] = mfma16(af[i], wf[j], acc[i][j]);
    }
    __syncthreads();
  }
#pragma unroll
  for (int i = 0; i < 4; ++i)
#pragma unroll
    for (int j = 0; j < 2; ++j)
#pragma unroll
      for (int r = 0; r < 4; ++r) {
        int row = m0 + wm + i * 16 + quad * 4 + r;
        int col = n0 + wn + j * 16 + lq;
        C[(size_t)row * N + col] = acc[i][j][r];
      }
}

// ---------------- Flash attention: S-transposed, no-max softmax, intra-block split-K ----------------
// BEST-KNOWN-GOOD (r7): LDS DMA staging, DOUBLE-buffered K/V, 1 barrier/iter, 2 blocks/CU.
// The dbuf is load-bearing for CORRECTNESS, not just speed: single-buffer (r10) raced
// (staging writes vs other waves' reads around the barrier) and failed absmax.
// Register-resident K/V (r8): 2x slower (per-wave vmcnt stalls at 2 waves/SIMD).
// Per-head softmax fusion (r9): 12% slower (serialized Pt write->read lgkmcnt waits).
// Plateau: 893 TF effective = 43% of 2075 TF ubench MFMA ceiling, MfmaUtil 38.5%.
__global__ __launch_bounds__(256, 2) void flash_attn(const bf16* __restrict__ QKV,
                                                     const bf16* __restrict__ Vt,
                                                     bf16* __restrict__ O) {
  const int bid = blockIdx.x;
  const int bg = (bid & 7) >> 1;                 // 0..3 -> (b,g), XCD-clustered
  const int b = bg >> 1, g = bg & 1;
  const int qt = ((bid >> 3) << 1) | (bid & 1);  // 0..127
  const int q0 = qt * 32;

  const int tid = threadIdx.x;
  const int w = tid >> 6, lane = tid & 63;
  const int half = w >> 1, wp = w & 1;           // KV-half, index within pair
  const int quad = lane >> 4, lq = lane & 15;

  __shared__ __align__(16) char smem[77824];
  bf16* Ks = (bf16*)smem;            // [buf][half][32*128], chunk c at c^(trow&15)
  bf16* Vs = (bf16*)(smem + 32768);  // [buf][half][128*32], chunk c at c^((drow>>1)&3)
  bf16* Pt = (bf16*)(smem + 65536);  // [wave][head][16*32], chunk c at c^((m>>1)&3)

  const bf16* Kgh = QKV + (size_t)b * S * NQKV + H * HD + g * HD + (size_t)half * 2048 * NQKV;
  const bf16* Vgh = Vt + (size_t)(b * HK + g) * HD * S + half * 2048;

  auto stage = [&](int t0, int buf) {
    bf16* kd = Ks + (buf * 2 + half) * 4096;
    bf16* vd = Vs + (buf * 2 + half) * 4096;
#pragma unroll
    for (int i = 0; i < 4; ++i) {
      int ig = wp * 4 + i;                 // 0..7
      int tl = ig * 4 + (lane >> 4);       // 0..31
      int c = (lane & 15) ^ (tl & 15);
      gld_lds16(Kgh + (size_t)(t0 + tl) * NQKV + c * 8, kd + ig * 512);
    }
#pragma unroll
    for (int i = 0; i < 4; ++i) {
      int ig = wp * 4 + i;
      int dl = ig * 16 + (lane >> 2);      // 0..127
      int c = (lane & 3) ^ ((dl >> 1) & 3);
      gld_lds16(Vgh + (size_t)dl * S + t0 + c * 8, vd + ig * 512);
    }
  };

  stage(0, 0);  // prologue

  // Q fragments: B-operand layout (n=lane&15 -> q-row, k=quad*8+j -> d)
  const bf16* Qg = QKV + ((size_t)b * S + q0 + wp * 16 + lq) * NQKV + g * REP * HD;
  bf16x8 qf[3][4];
#pragma unroll
  for (int u = 0; u < 3; ++u)
#pragma unroll
    for (int kk = 0; kk < 4; ++kk)
      qf[u][kk] = *(const bf16x8*)(Qg + u * HD + kk * 32 + quad * 8);

  bf16x8 ones;
#pragma unroll
  for (int j = 0; j < 8; ++j) ones[j] = (short)0x3F80;  // bf16 1.0

  floatx4 o[3][8] = {};
  floatx4 lacc[3] = {};           // denominator via ones-MFMA (all regs = row-sum)
  const int sw = (lq >> 1) & 3;   // swizzle key

#pragma unroll 2
  for (int it = 0; it < 64; ++it) {
    const int cur = it & 1;
    __syncthreads();  // drains this wave's DMA (vmcnt) + all waves' prior-iter LDS use
    if (it + 1 < 64) stage((it + 1) * 32, cur ^ 1);

    const bf16* ks = Ks + (cur * 2 + half) * 4096;
    const bf16* vs = Vs + (cur * 2 + half) * 4096;

    // ---- S^T = K Q^T : kf read once, reused by 3 heads ----
    floatx4 sf[3][2] = {};
#pragma unroll
    for (int tt = 0; tt < 2; ++tt)
#pragma unroll
      for (int kk = 0; kk < 4; ++kk) {
        int c = (kk * 4 + quad) ^ lq;  // t row = tt*16+lq -> key lq
        bf16x8 kf = *(const bf16x8*)&ks[(tt * 16 + lq) * 128 + c * 8];
#pragma unroll
        for (int u = 0; u < 3; ++u) sf[u][tt] = mfma16(kf, qf[u][kk], sf[u][tt]);
      }

    // ---- p = exp2(s); write P^T packed b64 (batch form: one write->read wait, all heads) ----
#pragma unroll
    for (int u = 0; u < 3; ++u) {
      char* ptb = (char*)(Pt + (w * 3 + u) * 512);
#pragma unroll
      for (int tt = 0; tt < 2; ++tt) {
        float p0 = EXP2F(sf[u][tt][0]), p1 = EXP2F(sf[u][tt][1]);
        float p2 = EXP2F(sf[u][tt][2]), p3 = EXP2F(sf[u][tt][3]);
        uint2 pkv;
        pkv.x = pk2(p0, p1);
        pkv.y = pk2(p2, p3);
        int cc = (tt * 2 + (quad >> 1)) ^ sw;
        *(uint2*)(ptb + lq * 64 + cc * 16 + (quad & 1) * 8) = pkv;
      }
    }

    // ---- read P^T B-frags (same-wave LDS, in-order) ----
    bf16x8 pf[3];
#pragma unroll
    for (int u = 0; u < 3; ++u) {
      const char* ptb = (const char*)(Pt + (w * 3 + u) * 512);
      pf[u] = *(const bf16x8*)(ptb + lq * 64 + ((quad ^ sw) * 16));
    }

    // ---- denominators: l += 1^T P^T ----
#pragma unroll
    for (int u = 0; u < 3; ++u) lacc[u] = mfma16(ones, pf[u], lacc[u]);

    // ---- O^T += V^T P^T : vf read once, reused by 3 heads ----
#pragma unroll
    for (int dd = 0; dd < 8; ++dd) {
      bf16x8 vf = *(const bf16x8*)&vs[(dd * 16 + lq) * 32 + ((quad ^ sw) * 8)];
#pragma unroll
      for (int u = 0; u < 3; ++u) o[u][dd] = mfma16(vf, pf[u], o[u][dd]);
    }
  }

  // ---- combine halves in LDS (overlay on Ks/Vs region), then store ----
  __syncthreads();  // all waves done reading K/V/P
  floatx4* oscr = (floatx4*)smem;           // [pair_slot(0..5)][dd][lane]
  float* lscr = (float*)(smem + 49152);     // [pair_slot][lane]
  if (half == 1) {
#pragma unroll
    for (int u = 0; u < 3; ++u) {
#pragma unroll
      for (int dd = 0; dd < 8; ++dd)
        oscr[((wp * 3 + u) * 8 + dd) * 64 + lane] = o[u][dd];
      lscr[(wp * 3 + u) * 64 + lane] = lacc[u][0];
    }
  }
  __syncthreads();
  if (half == 0) {
    const size_t row = (size_t)b * S + q0 + wp * 16 + lq;
#pragma unroll
    for (int u = 0; u < 3; ++u) {
      float l = lacc[u][0] + lscr[(wp * 3 + u) * 64 + lane];
      float rinv = 1.0f / l;
#pragma unroll
      for (int dd = 0; dd < 8; ++dd) {
        floatx4 oc = o[u][dd] + oscr[((wp * 3 + u) * 8 + dd) * 64 + lane];
        uint2 st;
        st.x = pk2(oc[0] * rinv, oc[1] * rinv);
        st.y = pk2(oc[2] * rinv, oc[3] * rinv);
        int col = (g * REP + u) * HD + dd * 16 + quad * 4;
        *(uint2*)&O[row * (H * HD) + col] = st;
      }
    }
  }
}

// ---------------- launch ----------------
static inline size_t al256(size_t x) { return (x + 255) & ~size_t(255); }

extern "C" void kernel_launch(void* const* d_in, const int* in_sizes, int n_in,
                              void* d_out, int out_size, void* d_ws, size_t ws_size,
                              hipStream_t stream) {
  const float* x  = (const float*)d_in[0];
  const float* wq = (const float*)d_in[1];
  const float* wk = (const float*)d_in[2];
  const float* wv = (const float*)d_in[3];
  const float* wo = (const float*)d_in[4];
  float* out = (float*)d_out;

  char* w = (char*)d_ws;
  size_t off = 0;
  auto carve = [&](size_t elems) {
    bf16* p = (bf16*)(w + off);
    off = al256(off + elems * sizeof(bf16));
    return p;
  };
  bf16* xb    = carve((size_t)M_ROWS * D);
  bf16* wqkvb = carve((size_t)NQKV * D);  // wq(768) | wk(256) | wv(256) rows
  bf16* wob   = carve((size_t)D * (H * HD));
  bf16* QKVb  = carve((size_t)M_ROWS * NQKV);
  bf16* Vtb   = carve((size_t)M_ROWS * (HK * HD));
  bf16* Ab    = carve((size_t)M_ROWS * (H * HD));

  // (1/sqrt(128)) * log2(e), folded into wq: scores come out in log2 domain
  const float qscale = 0.1275174465f;

  cvt_all<<<(int)(E_WO / 1024), 256, 0, stream>>>(x, wq, wk, wv, wo, xb, wqkvb, wob, qscale);

  // fused QKV projection: [8192,768] x [1280,768]^T -> [8192,1280]; V tiles -> Vt transposed
  gemm_bt<bf16, true><<<dim3(M_ROWS / 128, NQKV / 128), 256, 0, stream>>>(
      xb, wqkvb, QKVb, Vtb, M_ROWS, NQKV, D);

  flash_attn<<<512, 256, 0, stream>>>(QKVb, Vtb, Ab);

  // out projection: 128x64 tiles -> 768 blocks (exactly 3/CU x 256 CUs, 12 waves/CU)
  gemm_out<<<dim3(M_ROWS / 128, D / 64), 256, 0, stream>>>(
      Ab, wob, out, M_ROWS, D, H * HD);
}